// Round 1
// baseline (19725.650 us; speedup 1.0000x reference)
//
#include <hip/hip_runtime.h>
#include <cstdint>
#include <cstddef>

#define HCH 192
#define ICH 64
#define NRAD 6
#define SBFD 42

constexpr int BM = 32;   // rows per block
constexpr int NT = 256;  // threads per block
constexpr int BK = 32;   // K chunk for B staging

enum { EPI_BIAS_SILU = 0, EPI_RBF = 1, EPI_SILU = 2, EPI_ADDIN = 3, EPI_PLUSX = 4 };

__device__ __forceinline__ float silu_f(float v) {
    return v / (1.0f + __expf(-v));
}

// C[M,N] = epilogue(A[M,K] @ W[K,N]); BM rows per block, full N width per block.
// Full-K A tile staged (transposed) in LDS up-front -> in-place (out==A) is safe:
// each block reads only the rows it writes, and reads them all before writing.
template<int KDIM, int NDIM, int EPI>
__global__ __launch_bounds__(NT) void gemm_k(
    const float* __restrict__ A, const float* __restrict__ W,
    const float* __restrict__ bias, float* __restrict__ out,
    const float* __restrict__ aux,      // rbf (EPI_RBF) or x (EPI_PLUSX)
    const float* __restrict__ wc_rbf,   // [6,192] combined rbf weight (EPI_RBF)
    int E)
{
    constexpr int TN = NDIM / 16;       // 12 (N=192) or 4 (N=64)
    __shared__ float a_s[KDIM][BM + 2]; // transposed A tile, padded stride 34
    __shared__ float b_s[BK][NDIM];
    __shared__ float wc_s[(EPI == EPI_RBF) ? NRAD * HCH : 4];

    const int tid = threadIdx.x;
    const int row0 = blockIdx.x * BM;
    const int mg = tid & 15, ng = tid >> 4;
    const int m0 = mg * 2, n0 = ng * TN;

    // stage A (transpose into a_s[k][m])
    for (int i = tid; i < BM * KDIM / 4; i += NT) {
        int r = i / (KDIM / 4);
        int kq = (i % (KDIM / 4)) * 4;
        int rr = row0 + r;
        float4 v = make_float4(0.f, 0.f, 0.f, 0.f);
        if (rr < E) v = *(const float4*)(A + (size_t)rr * KDIM + kq);
        a_s[kq + 0][r] = v.x; a_s[kq + 1][r] = v.y;
        a_s[kq + 2][r] = v.z; a_s[kq + 3][r] = v.w;
    }
    if (EPI == EPI_RBF) {
        for (int i = tid; i < NRAD * HCH / 4; i += NT)
            *(float4*)&wc_s[i * 4] = *(const float4*)(wc_rbf + i * 4);
    }

    float acc[2][TN];
    #pragma unroll
    for (int i = 0; i < 2; ++i)
        #pragma unroll
        for (int j = 0; j < TN; ++j) acc[i][j] = 0.f;

    for (int c = 0; c < KDIM / BK; ++c) {
        __syncthreads();
        for (int i = tid; i < BK * NDIM / 4; i += NT) {
            int kk = i / (NDIM / 4);
            int cq = (i % (NDIM / 4)) * 4;
            *(float4*)&b_s[kk][cq] = *(const float4*)(W + (size_t)(c * BK + kk) * NDIM + cq);
        }
        __syncthreads();
        #pragma unroll
        for (int kk = 0; kk < BK; ++kk) {
            float2 a2 = *(const float2*)&a_s[c * BK + kk][m0];
            #pragma unroll
            for (int j4 = 0; j4 < TN / 4; ++j4) {
                float4 b4 = *(const float4*)&b_s[kk][n0 + j4 * 4];
                acc[0][j4*4+0] += a2.x * b4.x; acc[0][j4*4+1] += a2.x * b4.y;
                acc[0][j4*4+2] += a2.x * b4.z; acc[0][j4*4+3] += a2.x * b4.w;
                acc[1][j4*4+0] += a2.y * b4.x; acc[1][j4*4+1] += a2.y * b4.y;
                acc[1][j4*4+2] += a2.y * b4.z; acc[1][j4*4+3] += a2.y * b4.w;
            }
        }
    }

    float rb[2][NRAD];
    if (EPI == EPI_RBF) {
        #pragma unroll
        for (int i = 0; i < 2; ++i) {
            int rr = row0 + m0 + i;
            if (rr < E) {
                const float* rp = aux + (size_t)rr * NRAD;
                #pragma unroll
                for (int r = 0; r < NRAD; ++r) rb[i][r] = rp[r];
            }
        }
    }

    #pragma unroll
    for (int i = 0; i < 2; ++i) {
        int rr = row0 + m0 + i;
        if (rr >= E) continue;
        size_t orow = (size_t)rr * NDIM;
        #pragma unroll
        for (int j4 = 0; j4 < TN / 4; ++j4) {
            float ov[4];
            #pragma unroll
            for (int u = 0; u < 4; ++u) {
                int col = n0 + j4 * 4 + u;
                float v = acc[i][j4 * 4 + u];
                if (EPI == EPI_BIAS_SILU || EPI == EPI_RBF || EPI == EPI_PLUSX) v += bias[col];
                float sv = silu_f(v);
                if (EPI == EPI_RBF) {
                    float rh = 0.f;
                    #pragma unroll
                    for (int r = 0; r < NRAD; ++r) rh += rb[i][r] * wc_s[r * HCH + col];
                    sv *= rh;
                }
                ov[u] = sv;
            }
            float4 o = make_float4(ov[0], ov[1], ov[2], ov[3]);
            if (EPI == EPI_ADDIN) {
                float4 p = *(const float4*)(out + orow + n0 + j4 * 4);
                o.x += p.x; o.y += p.y; o.z += p.z; o.w += p.w;
            }
            if (EPI == EPI_PLUSX) {
                float4 xv = *(const float4*)(aux + orow + n0 + j4 * 4);
                o.x += xv.x; o.y += xv.y; o.z += xv.z; o.w += xv.w;
            }
            *(float4*)(out + orow + n0 + j4 * 4) = o;
        }
    }
}

// Fused residual layer: hdst = hsrc + silu(silu(hsrc@W0 + b0) @ W1 + b1)
// Block owns BM full rows -> in-place safe.
__global__ __launch_bounds__(NT) void resfused_k(
    const float* __restrict__ hsrc, float* __restrict__ hdst,
    const float* __restrict__ Wp,  // [2,192,192]
    const float* __restrict__ bp,  // [2,192]
    int E)
{
    __shared__ float h_s[HCH][BM + 2];
    __shared__ float t_s[HCH][BM + 2];
    __shared__ float w_s[BK][HCH];

    const int tid = threadIdx.x;
    const int row0 = blockIdx.x * BM;
    const int mg = tid & 15, ng = tid >> 4;
    const int m0 = mg * 2, n0 = ng * 12;

    for (int i = tid; i < BM * HCH / 4; i += NT) {
        int r = i / (HCH / 4);
        int kq = (i % (HCH / 4)) * 4;
        int rr = row0 + r;
        float4 v = make_float4(0.f, 0.f, 0.f, 0.f);
        if (rr < E) v = *(const float4*)(hsrc + (size_t)rr * HCH + kq);
        h_s[kq + 0][r] = v.x; h_s[kq + 1][r] = v.y;
        h_s[kq + 2][r] = v.z; h_s[kq + 3][r] = v.w;
    }

    float acc[2][12];
    #pragma unroll
    for (int i = 0; i < 2; ++i)
        #pragma unroll
        for (int j = 0; j < 12; ++j) acc[i][j] = 0.f;

    // GEMM 1: t = silu(h @ W0 + b0)
    for (int c = 0; c < HCH / BK; ++c) {
        __syncthreads();
        for (int i = tid; i < BK * HCH / 4; i += NT) {
            int kk = i / (HCH / 4);
            int cq = (i % (HCH / 4)) * 4;
            *(float4*)&w_s[kk][cq] = *(const float4*)(Wp + (size_t)(c * BK + kk) * HCH + cq);
        }
        __syncthreads();
        #pragma unroll
        for (int kk = 0; kk < BK; ++kk) {
            float2 a2 = *(const float2*)&h_s[c * BK + kk][m0];
            #pragma unroll
            for (int j4 = 0; j4 < 3; ++j4) {
                float4 b4 = *(const float4*)&w_s[kk][n0 + j4 * 4];
                acc[0][j4*4+0] += a2.x * b4.x; acc[0][j4*4+1] += a2.x * b4.y;
                acc[0][j4*4+2] += a2.x * b4.z; acc[0][j4*4+3] += a2.x * b4.w;
                acc[1][j4*4+0] += a2.y * b4.x; acc[1][j4*4+1] += a2.y * b4.y;
                acc[1][j4*4+2] += a2.y * b4.z; acc[1][j4*4+3] += a2.y * b4.w;
            }
        }
    }
    #pragma unroll
    for (int i = 0; i < 2; ++i)
        #pragma unroll
        for (int j = 0; j < 12; ++j) {
            int col = n0 + j;
            t_s[col][m0 + i] = silu_f(acc[i][j] + bp[col]);
            acc[i][j] = 0.f;
        }

    // GEMM 2: out = h + silu(t @ W1 + b1)
    const float* W1 = Wp + (size_t)HCH * HCH;
    for (int c = 0; c < HCH / BK; ++c) {
        __syncthreads();
        for (int i = tid; i < BK * HCH / 4; i += NT) {
            int kk = i / (HCH / 4);
            int cq = (i % (HCH / 4)) * 4;
            *(float4*)&w_s[kk][cq] = *(const float4*)(W1 + (size_t)(c * BK + kk) * HCH + cq);
        }
        __syncthreads();
        #pragma unroll
        for (int kk = 0; kk < BK; ++kk) {
            float2 a2 = *(const float2*)&t_s[c * BK + kk][m0];
            #pragma unroll
            for (int j4 = 0; j4 < 3; ++j4) {
                float4 b4 = *(const float4*)&w_s[kk][n0 + j4 * 4];
                acc[0][j4*4+0] += a2.x * b4.x; acc[0][j4*4+1] += a2.x * b4.y;
                acc[0][j4*4+2] += a2.x * b4.z; acc[0][j4*4+3] += a2.x * b4.w;
                acc[1][j4*4+0] += a2.y * b4.x; acc[1][j4*4+1] += a2.y * b4.y;
                acc[1][j4*4+2] += a2.y * b4.z; acc[1][j4*4+3] += a2.y * b4.w;
            }
        }
    }
    #pragma unroll
    for (int i = 0; i < 2; ++i) {
        int rr = row0 + m0 + i;
        if (rr >= E) continue;
        size_t orow = (size_t)rr * HCH;
        #pragma unroll
        for (int j4 = 0; j4 < 3; ++j4) {
            float ov[4];
            #pragma unroll
            for (int u = 0; u < 4; ++u) {
                int col = n0 + j4 * 4 + u;
                ov[u] = h_s[col][m0 + i] + silu_f(acc[i][j4 * 4 + u] + bp[HCH + col]);
            }
            *(float4*)(hdst + orow + n0 + j4 * 4) = make_float4(ov[0], ov[1], ov[2], ov[3]);
        }
    }
}

// Per-triplet: sbf_i = (sbf@W1)@W2 (factored, 848 MACs); m = x64[idx_kj]*sbf_i;
// atomicAdd into agg[idx_ji]. Weights read with uniform (scalar-pipe) loads.
__global__ __launch_bounds__(NT) void scatter_k(
    const float* __restrict__ sbf, const int* __restrict__ idx_kj,
    const int* __restrict__ idx_ji, const float* __restrict__ x64,
    const float* __restrict__ w1,   // [42,8]
    const float* __restrict__ w2,   // [8,64]
    float* __restrict__ agg, int T)
{
    int t = blockIdx.x * NT + threadIdx.x;
    if (t >= T) return;

    float s[SBFD];
    const float* sp = sbf + (size_t)t * SBFD;
    #pragma unroll
    for (int i = 0; i < SBFD / 2; ++i) {
        float2 v = *(const float2*)(sp + i * 2);
        s[2 * i] = v.x; s[2 * i + 1] = v.y;
    }
    float p[8];
    #pragma unroll
    for (int b = 0; b < 8; ++b) p[b] = 0.f;
    #pragma unroll
    for (int r = 0; r < SBFD; ++r) {
        float sv = s[r];
        #pragma unroll
        for (int b = 0; b < 8; ++b) p[b] += sv * w1[r * 8 + b];
    }

    int kj = idx_kj[t], ji = idx_ji[t];
    const float* g = x64 + (size_t)kj * ICH;
    float* arow = agg + (size_t)ji * ICH;

    #pragma unroll
    for (int c = 0; c < ICH / 16; ++c) {
        float acc[16];
        #pragma unroll
        for (int i = 0; i < 16; ++i) acc[i] = 0.f;
        #pragma unroll
        for (int b = 0; b < 8; ++b) {
            float pb = p[b];
            #pragma unroll
            for (int i = 0; i < 16; ++i) acc[i] += pb * w2[b * ICH + c * 16 + i];
        }
        #pragma unroll
        for (int i = 0; i < 16; i += 4) {
            float4 gv = *(const float4*)(g + c * 16 + i);
            atomicAdd(arow + c * 16 + i + 0, acc[i + 0] * gv.x);
            atomicAdd(arow + c * 16 + i + 1, acc[i + 1] * gv.y);
            atomicAdd(arow + c * 16 + i + 2, acc[i + 2] * gv.z);
            atomicAdd(arow + c * 16 + i + 3, acc[i + 3] * gv.w);
        }
    }
}

// wc_rbf[6,192] = W_rbf1[6,8] @ W_rbf2[8,192]
__global__ void wc_k(const float* __restrict__ W_rbf1, const float* __restrict__ W_rbf2,
                     float* __restrict__ wc)
{
    int tid = blockIdx.x * blockDim.x + threadIdx.x;
    if (tid < NRAD * HCH) {
        int r = tid / HCH, c = tid % HCH;
        float a = 0.f;
        #pragma unroll
        for (int b = 0; b < 8; ++b) a += W_rbf1[r * 8 + b] * W_rbf2[b * HCH + c];
        wc[tid] = a;
    }
}

extern "C" void kernel_launch(void* const* d_in, const int* in_sizes, int n_in,
                              void* d_out, int out_size, void* d_ws, size_t ws_size,
                              hipStream_t stream) {
    const float* x      = (const float*)d_in[0];
    const float* rbf    = (const float*)d_in[1];
    const float* sbf    = (const float*)d_in[2];
    const int*   idx_kj = (const int*)d_in[3];
    const int*   idx_ji = (const int*)d_in[4];
    const float* W_rbf1 = (const float*)d_in[5];
    const float* W_rbf2 = (const float*)d_in[6];
    const float* W_sbf1 = (const float*)d_in[7];
    const float* W_sbf2 = (const float*)d_in[8];
    const float* W_kj   = (const float*)d_in[9];
    const float* b_kj   = (const float*)d_in[10];
    const float* W_ji   = (const float*)d_in[11];
    const float* b_ji   = (const float*)d_in[12];
    const float* W_down = (const float*)d_in[13];
    const float* W_up   = (const float*)d_in[14];
    const float* resbW  = (const float*)d_in[15];
    const float* resbB  = (const float*)d_in[16];
    const float* W_lin  = (const float*)d_in[17];
    const float* b_lin  = (const float*)d_in[18];
    const float* resaW  = (const float*)d_in[19];
    const float* resaB  = (const float*)d_in[20];

    const int E = in_sizes[0] / HCH;
    const int T = in_sizes[3];
    float* out = (float*)d_out;

    // workspace: agg[E,64] | x64[E,64] | wc_rbf[6,192]  (~205 MB)
    float* agg    = (float*)d_ws;
    float* x64    = agg + (size_t)E * ICH;
    float* wc_rbf = x64 + (size_t)E * ICH;

    const int gb = (E + BM - 1) / BM;

    wc_k<<<(NRAD * HCH + NT - 1) / NT, NT, 0, stream>>>(W_rbf1, W_rbf2, wc_rbf);

    // x_kj = silu(x@W_kj + b_kj) * rbf_h   -> d_out (scratch use)
    gemm_k<192, 192, EPI_RBF><<<gb, NT, 0, stream>>>(x, W_kj, b_kj, out, rbf, wc_rbf, E);
    // x64 = silu(x_kj @ W_down)
    gemm_k<192, 64, EPI_SILU><<<gb, NT, 0, stream>>>(out, W_down, nullptr, x64, nullptr, nullptr, E);
    // agg = segment_sum(x64[idx_kj] * sbf_i, idx_ji)
    hipMemsetAsync(agg, 0, (size_t)E * ICH * sizeof(float), stream);
    scatter_k<<<(T + NT - 1) / NT, NT, 0, stream>>>(sbf, idx_kj, idx_ji, x64, W_sbf1, W_sbf2, agg, T);
    // x_ji = silu(x@W_ji + b_ji) -> d_out (overwrite)
    gemm_k<192, 192, EPI_BIAS_SILU><<<gb, NT, 0, stream>>>(x, W_ji, b_ji, out, nullptr, nullptr, E);
    // h = x_ji + silu(agg @ W_up)   (in-place element add)
    gemm_k<64, 192, EPI_ADDIN><<<gb, NT, 0, stream>>>(agg, W_up, nullptr, out, nullptr, nullptr, E);
    // res_before layer 0 (in place)
    resfused_k<<<gb, NT, 0, stream>>>(out, out, resbW, resbB, E);
    // h = silu(h@W_lin + b_lin) + x   (in place; block owns full rows)
    gemm_k<192, 192, EPI_PLUSX><<<gb, NT, 0, stream>>>(out, W_lin, b_lin, out, x, nullptr, E);
    // res_after layers 0,1 (in place)
    resfused_k<<<gb, NT, 0, stream>>>(out, out, resaW, resaB, E);
    resfused_k<<<gb, NT, 0, stream>>>(out, out, resaW + 2 * HCH * HCH, resaB + 2 * HCH, E);
}

// Round 2
// 7175.050 us; speedup vs baseline: 2.7492x; 2.7492x over previous
//
#include <hip/hip_runtime.h>
#include <cstdint>
#include <cstddef>

#define HCH 192
#define ICH 64
#define NRAD 6
#define SBFD 42

constexpr int BM = 32;   // rows per block
constexpr int NT = 256;  // threads per block
constexpr int BK = 32;   // K chunk for B staging

enum { EPI_BIAS_SILU = 0, EPI_RBF = 1, EPI_SILU = 2, EPI_ADDIN = 3, EPI_PLUSX = 4 };

__device__ __forceinline__ float silu_f(float v) {
    return v / (1.0f + __expf(-v));
}

// ---------------- GEMM stack (unchanged from round 0) ----------------
template<int KDIM, int NDIM, int EPI>
__global__ __launch_bounds__(NT) void gemm_k(
    const float* __restrict__ A, const float* __restrict__ W,
    const float* __restrict__ bias, float* __restrict__ out,
    const float* __restrict__ aux,      // rbf (EPI_RBF) or x (EPI_PLUSX)
    const float* __restrict__ wc_rbf,   // [6,192] combined rbf weight (EPI_RBF)
    int E)
{
    constexpr int TN = NDIM / 16;
    __shared__ float a_s[KDIM][BM + 2];
    __shared__ float b_s[BK][NDIM];
    __shared__ float wc_s[(EPI == EPI_RBF) ? NRAD * HCH : 4];

    const int tid = threadIdx.x;
    const int row0 = blockIdx.x * BM;
    const int mg = tid & 15, ng = tid >> 4;
    const int m0 = mg * 2, n0 = ng * TN;

    for (int i = tid; i < BM * KDIM / 4; i += NT) {
        int r = i / (KDIM / 4);
        int kq = (i % (KDIM / 4)) * 4;
        int rr = row0 + r;
        float4 v = make_float4(0.f, 0.f, 0.f, 0.f);
        if (rr < E) v = *(const float4*)(A + (size_t)rr * KDIM + kq);
        a_s[kq + 0][r] = v.x; a_s[kq + 1][r] = v.y;
        a_s[kq + 2][r] = v.z; a_s[kq + 3][r] = v.w;
    }
    if (EPI == EPI_RBF) {
        for (int i = tid; i < NRAD * HCH / 4; i += NT)
            *(float4*)&wc_s[i * 4] = *(const float4*)(wc_rbf + i * 4);
    }

    float acc[2][TN];
    #pragma unroll
    for (int i = 0; i < 2; ++i)
        #pragma unroll
        for (int j = 0; j < TN; ++j) acc[i][j] = 0.f;

    for (int c = 0; c < KDIM / BK; ++c) {
        __syncthreads();
        for (int i = tid; i < BK * NDIM / 4; i += NT) {
            int kk = i / (NDIM / 4);
            int cq = (i % (NDIM / 4)) * 4;
            *(float4*)&b_s[kk][cq] = *(const float4*)(W + (size_t)(c * BK + kk) * NDIM + cq);
        }
        __syncthreads();
        #pragma unroll
        for (int kk = 0; kk < BK; ++kk) {
            float2 a2 = *(const float2*)&a_s[c * BK + kk][m0];
            #pragma unroll
            for (int j4 = 0; j4 < TN / 4; ++j4) {
                float4 b4 = *(const float4*)&b_s[kk][n0 + j4 * 4];
                acc[0][j4*4+0] += a2.x * b4.x; acc[0][j4*4+1] += a2.x * b4.y;
                acc[0][j4*4+2] += a2.x * b4.z; acc[0][j4*4+3] += a2.x * b4.w;
                acc[1][j4*4+0] += a2.y * b4.x; acc[1][j4*4+1] += a2.y * b4.y;
                acc[1][j4*4+2] += a2.y * b4.z; acc[1][j4*4+3] += a2.y * b4.w;
            }
        }
    }

    float rb[2][NRAD];
    if (EPI == EPI_RBF) {
        #pragma unroll
        for (int i = 0; i < 2; ++i) {
            int rr = row0 + m0 + i;
            if (rr < E) {
                const float* rp = aux + (size_t)rr * NRAD;
                #pragma unroll
                for (int r = 0; r < NRAD; ++r) rb[i][r] = rp[r];
            }
        }
    }

    #pragma unroll
    for (int i = 0; i < 2; ++i) {
        int rr = row0 + m0 + i;
        if (rr >= E) continue;
        size_t orow = (size_t)rr * NDIM;
        #pragma unroll
        for (int j4 = 0; j4 < TN / 4; ++j4) {
            float ov[4];
            #pragma unroll
            for (int u = 0; u < 4; ++u) {
                int col = n0 + j4 * 4 + u;
                float v = acc[i][j4 * 4 + u];
                if (EPI == EPI_BIAS_SILU || EPI == EPI_RBF || EPI == EPI_PLUSX) v += bias[col];
                float sv = silu_f(v);
                if (EPI == EPI_RBF) {
                    float rh = 0.f;
                    #pragma unroll
                    for (int r = 0; r < NRAD; ++r) rh += rb[i][r] * wc_s[r * HCH + col];
                    sv *= rh;
                }
                ov[u] = sv;
            }
            float4 o = make_float4(ov[0], ov[1], ov[2], ov[3]);
            if (EPI == EPI_ADDIN) {
                float4 p = *(const float4*)(out + orow + n0 + j4 * 4);
                o.x += p.x; o.y += p.y; o.z += p.z; o.w += p.w;
            }
            if (EPI == EPI_PLUSX) {
                float4 xv = *(const float4*)(aux + orow + n0 + j4 * 4);
                o.x += xv.x; o.y += xv.y; o.z += xv.z; o.w += xv.w;
            }
            *(float4*)(out + orow + n0 + j4 * 4) = o;
        }
    }
}

__global__ __launch_bounds__(NT) void resfused_k(
    const float* __restrict__ hsrc, float* __restrict__ hdst,
    const float* __restrict__ Wp, const float* __restrict__ bp, int E)
{
    __shared__ float h_s[HCH][BM + 2];
    __shared__ float t_s[HCH][BM + 2];
    __shared__ float w_s[BK][HCH];

    const int tid = threadIdx.x;
    const int row0 = blockIdx.x * BM;
    const int mg = tid & 15, ng = tid >> 4;
    const int m0 = mg * 2, n0 = ng * 12;

    for (int i = tid; i < BM * HCH / 4; i += NT) {
        int r = i / (HCH / 4);
        int kq = (i % (HCH / 4)) * 4;
        int rr = row0 + r;
        float4 v = make_float4(0.f, 0.f, 0.f, 0.f);
        if (rr < E) v = *(const float4*)(hsrc + (size_t)rr * HCH + kq);
        h_s[kq + 0][r] = v.x; h_s[kq + 1][r] = v.y;
        h_s[kq + 2][r] = v.z; h_s[kq + 3][r] = v.w;
    }

    float acc[2][12];
    #pragma unroll
    for (int i = 0; i < 2; ++i)
        #pragma unroll
        for (int j = 0; j < 12; ++j) acc[i][j] = 0.f;

    for (int c = 0; c < HCH / BK; ++c) {
        __syncthreads();
        for (int i = tid; i < BK * HCH / 4; i += NT) {
            int kk = i / (HCH / 4);
            int cq = (i % (HCH / 4)) * 4;
            *(float4*)&w_s[kk][cq] = *(const float4*)(Wp + (size_t)(c * BK + kk) * HCH + cq);
        }
        __syncthreads();
        #pragma unroll
        for (int kk = 0; kk < BK; ++kk) {
            float2 a2 = *(const float2*)&h_s[c * BK + kk][m0];
            #pragma unroll
            for (int j4 = 0; j4 < 3; ++j4) {
                float4 b4 = *(const float4*)&w_s[kk][n0 + j4 * 4];
                acc[0][j4*4+0] += a2.x * b4.x; acc[0][j4*4+1] += a2.x * b4.y;
                acc[0][j4*4+2] += a2.x * b4.z; acc[0][j4*4+3] += a2.x * b4.w;
                acc[1][j4*4+0] += a2.y * b4.x; acc[1][j4*4+1] += a2.y * b4.y;
                acc[1][j4*4+2] += a2.y * b4.z; acc[1][j4*4+3] += a2.y * b4.w;
            }
        }
    }
    #pragma unroll
    for (int i = 0; i < 2; ++i)
        #pragma unroll
        for (int j = 0; j < 12; ++j) {
            int col = n0 + j;
            t_s[col][m0 + i] = silu_f(acc[i][j] + bp[col]);
            acc[i][j] = 0.f;
        }

    const float* W1 = Wp + (size_t)HCH * HCH;
    for (int c = 0; c < HCH / BK; ++c) {
        __syncthreads();
        for (int i = tid; i < BK * HCH / 4; i += NT) {
            int kk = i / (HCH / 4);
            int cq = (i % (HCH / 4)) * 4;
            *(float4*)&w_s[kk][cq] = *(const float4*)(W1 + (size_t)(c * BK + kk) * HCH + cq);
        }
        __syncthreads();
        #pragma unroll
        for (int kk = 0; kk < BK; ++kk) {
            float2 a2 = *(const float2*)&t_s[c * BK + kk][m0];
            #pragma unroll
            for (int j4 = 0; j4 < 3; ++j4) {
                float4 b4 = *(const float4*)&w_s[kk][n0 + j4 * 4];
                acc[0][j4*4+0] += a2.x * b4.x; acc[0][j4*4+1] += a2.x * b4.y;
                acc[0][j4*4+2] += a2.x * b4.z; acc[0][j4*4+3] += a2.x * b4.w;
                acc[1][j4*4+0] += a2.y * b4.x; acc[1][j4*4+1] += a2.y * b4.y;
                acc[1][j4*4+2] += a2.y * b4.z; acc[1][j4*4+3] += a2.y * b4.w;
            }
        }
    }
    #pragma unroll
    for (int i = 0; i < 2; ++i) {
        int rr = row0 + m0 + i;
        if (rr >= E) continue;
        size_t orow = (size_t)rr * HCH;
        #pragma unroll
        for (int j4 = 0; j4 < 3; ++j4) {
            float ov[4];
            #pragma unroll
            for (int u = 0; u < 4; ++u) {
                int col = n0 + j4 * 4 + u;
                ov[u] = h_s[col][m0 + i] + silu_f(acc[i][j4 * 4 + u] + bp[HCH + col]);
            }
            *(float4*)(hdst + orow + n0 + j4 * 4) = make_float4(ov[0], ov[1], ov[2], ov[3]);
        }
    }
}

// ---------------- CSR scatter->gather pipeline (replaces scatter_k) ----------------

// Pass A: p[t] = sbf[t] @ W_sbf1  (T x 8), plus histogram of idx_ji.
__global__ __launch_bounds__(256) void pcount_k(
    const float* __restrict__ sbf, const int* __restrict__ idx_ji,
    const float* __restrict__ w1,   // [42,8]
    float* __restrict__ p, int* __restrict__ counts, int T)
{
    int t = blockIdx.x * 256 + threadIdx.x;
    if (t >= T) return;
    const float* sp = sbf + (size_t)t * SBFD;
    float acc[8];
    #pragma unroll
    for (int b = 0; b < 8; ++b) acc[b] = 0.f;
    #pragma unroll
    for (int r = 0; r < SBFD; r += 2) {
        float2 v = *(const float2*)(sp + r);
        #pragma unroll
        for (int b = 0; b < 8; ++b)
            acc[b] += v.x * w1[r * 8 + b] + v.y * w1[(r + 1) * 8 + b];
    }
    float4* pp = (float4*)(p + (size_t)t * 8);
    pp[0] = make_float4(acc[0], acc[1], acc[2], acc[3]);
    pp[1] = make_float4(acc[4], acc[5], acc[6], acc[7]);
    atomicAdd(&counts[idx_ji[t]], 1);
}

// Prefix scan, 3 kernels. 1024 counts per block.
__global__ __launch_bounds__(256) void psum1_k(const int* __restrict__ counts,
                                               int* __restrict__ bsum, int E) {
    __shared__ int s[256];
    int base = blockIdx.x * 1024;
    int tid = threadIdx.x;
    int sum = 0;
    #pragma unroll
    for (int j = 0; j < 4; ++j) { int i = base + j * 256 + tid; if (i < E) sum += counts[i]; }
    s[tid] = sum; __syncthreads();
    for (int off = 128; off > 0; off >>= 1) {
        if (tid < off) s[tid] += s[tid + off];
        __syncthreads();
    }
    if (tid == 0) bsum[blockIdx.x] = s[0];
}

__global__ __launch_bounds__(512) void psum2_k(int* bsum, int G) {
    __shared__ int s[512];
    int tid = threadIdx.x;
    s[tid] = (tid < G) ? bsum[tid] : 0;
    for (int off = 1; off < 512; off <<= 1) {
        __syncthreads();
        int v = (tid >= off) ? s[tid - off] : 0;
        __syncthreads();
        s[tid] += v;
    }
    __syncthreads();
    if (tid < G) bsum[tid] = (tid == 0) ? 0 : s[tid - 1];
}

__global__ __launch_bounds__(256) void psum3_k(const int* __restrict__ counts,
                                               const int* __restrict__ bsum,
                                               int* __restrict__ start, int E) {
    __shared__ int s[256];
    int tid = threadIdx.x;
    int base = blockIdx.x * 1024 + tid * 4;
    int v[4]; int loc = 0;
    #pragma unroll
    for (int j = 0; j < 4; ++j) { v[j] = (base + j < E) ? counts[base + j] : 0; loc += v[j]; }
    s[tid] = loc;
    for (int off = 1; off < 256; off <<= 1) {
        __syncthreads();
        int t2 = (tid >= off) ? s[tid - off] : 0;
        __syncthreads();
        s[tid] += t2;
    }
    __syncthreads();
    int run = bsum[blockIdx.x] + s[tid] - loc;   // exclusive prefix
    #pragma unroll
    for (int j = 0; j < 4; ++j) { if (base + j < E) start[base + j] = run; run += v[j]; }
}

// Bucket triplet ids by ji. After this, start[e] == end offset of bucket e.
__global__ __launch_bounds__(256) void fill_k(const int* __restrict__ idx_ji,
                                              int* __restrict__ start,
                                              int* __restrict__ trip, int T) {
    int t = blockIdx.x * 256 + threadIdx.x;
    if (t >= T) return;
    int pos = atomicAdd(&start[idx_ji[t]], 1);
    trip[pos] = t;
}

// One wave per edge, lane = channel. agg[e,c] = sum over bucket of
// x64[kj,c] * (p[t] @ W2)[c]. No atomics, one clean store per edge.
__global__ __launch_bounds__(256) void gather_k(
    const int* __restrict__ trip, const int* __restrict__ idx_kj,
    const float* __restrict__ p, const float* __restrict__ x64,
    const int* __restrict__ start, const int* __restrict__ counts,
    const float* __restrict__ w2,   // [8,64]
    float* __restrict__ agg, int E)
{
    __shared__ float w2s[8 * 64];
    int tid = threadIdx.x;
    for (int i = tid; i < 8 * 64; i += 256) w2s[i] = w2[i];
    __syncthreads();

    int wave = (blockIdx.x * 256 + tid) >> 6;
    int lane = tid & 63;
    if (wave >= E) return;

    int n = counts[wave];
    int end = start[wave];        // post-fill: end of bucket
    int begin = end - n;

    float acc = 0.f;
    for (int i = begin; i < end; ++i) {
        int t = trip[i];
        int kj = idx_kj[t];
        float p8 = p[(size_t)t * 8 + (lane & 7)];
        float xv = x64[(size_t)kj * ICH + lane];
        float sc = 0.f;
        #pragma unroll
        for (int b = 0; b < 8; ++b)
            sc += __shfl(p8, b, 64) * w2s[b * 64 + lane];
        acc += sc * xv;
    }
    agg[(size_t)wave * ICH + lane] = acc;
}

// wc_rbf[6,192] = W_rbf1[6,8] @ W_rbf2[8,192]
__global__ void wc_k(const float* __restrict__ W_rbf1, const float* __restrict__ W_rbf2,
                     float* __restrict__ wc)
{
    int tid = blockIdx.x * blockDim.x + threadIdx.x;
    if (tid < NRAD * HCH) {
        int r = tid / HCH, c = tid % HCH;
        float a = 0.f;
        #pragma unroll
        for (int b = 0; b < 8; ++b) a += W_rbf1[r * 8 + b] * W_rbf2[b * HCH + c];
        wc[tid] = a;
    }
}

extern "C" void kernel_launch(void* const* d_in, const int* in_sizes, int n_in,
                              void* d_out, int out_size, void* d_ws, size_t ws_size,
                              hipStream_t stream) {
    const float* x      = (const float*)d_in[0];
    const float* rbf    = (const float*)d_in[1];
    const float* sbf    = (const float*)d_in[2];
    const int*   idx_kj = (const int*)d_in[3];
    const int*   idx_ji = (const int*)d_in[4];
    const float* W_rbf1 = (const float*)d_in[5];
    const float* W_rbf2 = (const float*)d_in[6];
    const float* W_sbf1 = (const float*)d_in[7];
    const float* W_sbf2 = (const float*)d_in[8];
    const float* W_kj   = (const float*)d_in[9];
    const float* b_kj   = (const float*)d_in[10];
    const float* W_ji   = (const float*)d_in[11];
    const float* b_ji   = (const float*)d_in[12];
    const float* W_down = (const float*)d_in[13];
    const float* W_up   = (const float*)d_in[14];
    const float* resbW  = (const float*)d_in[15];
    const float* resbB  = (const float*)d_in[16];
    const float* W_lin  = (const float*)d_in[17];
    const float* b_lin  = (const float*)d_in[18];
    const float* resaW  = (const float*)d_in[19];
    const float* resaB  = (const float*)d_in[20];

    const int E = in_sizes[0] / HCH;
    const int T = in_sizes[3];
    float* out = (float*)d_out;

    // workspace layout (floats first for 16B alignment):
    // p[T,8] | x64[E,64] | agg[E,64] | wc_rbf[6*192] | counts[E] | start[E] | bsum[512] | trip[T]
    float* p      = (float*)d_ws;
    float* x64    = p + (size_t)T * 8;
    float* agg    = x64 + (size_t)E * ICH;
    float* wc_rbf = agg + (size_t)E * ICH;
    int*   counts = (int*)(wc_rbf + NRAD * HCH);
    int*   start  = counts + E;
    int*   bsum   = start + E;
    int*   trip   = bsum + 512;

    const int gb = (E + BM - 1) / BM;
    const int gt = (T + 255) / 256;
    const int gscan = (E + 1023) / 1024;   // <= 512 blocks required by psum2

    wc_k<<<(NRAD * HCH + NT - 1) / NT, NT, 0, stream>>>(W_rbf1, W_rbf2, wc_rbf);

    // CSR build (independent of GEMMs)
    hipMemsetAsync(counts, 0, (size_t)E * sizeof(int), stream);
    pcount_k<<<gt, 256, 0, stream>>>(sbf, idx_ji, W_sbf1, p, counts, T);
    psum1_k<<<gscan, 256, 0, stream>>>(counts, bsum, E);
    psum2_k<<<1, 512, 0, stream>>>(bsum, gscan);
    psum3_k<<<gscan, 256, 0, stream>>>(counts, bsum, start, E);
    fill_k<<<gt, 256, 0, stream>>>(idx_ji, start, trip, T);

    // x_kj = silu(x@W_kj + b_kj) * rbf_h   -> d_out (scratch)
    gemm_k<192, 192, EPI_RBF><<<gb, NT, 0, stream>>>(x, W_kj, b_kj, out, rbf, wc_rbf, E);
    // x64 = silu(x_kj @ W_down)
    gemm_k<192, 64, EPI_SILU><<<gb, NT, 0, stream>>>(out, W_down, nullptr, x64, nullptr, nullptr, E);

    // agg = segment_sum(x64[idx_kj] * (p@W_sbf2), idx_ji)  — gather form, no atomics
    gather_k<<<(E + 3) / 4, 256, 0, stream>>>(trip, idx_kj, p, x64, start, counts, W_sbf2, agg, E);

    // x_ji = silu(x@W_ji + b_ji) -> d_out
    gemm_k<192, 192, EPI_BIAS_SILU><<<gb, NT, 0, stream>>>(x, W_ji, b_ji, out, nullptr, nullptr, E);
    // h = x_ji + silu(agg @ W_up)
    gemm_k<64, 192, EPI_ADDIN><<<gb, NT, 0, stream>>>(agg, W_up, nullptr, out, nullptr, nullptr, E);
    // res_before
    resfused_k<<<gb, NT, 0, stream>>>(out, out, resbW, resbB, E);
    // h = silu(h@W_lin + b_lin) + x
    gemm_k<192, 192, EPI_PLUSX><<<gb, NT, 0, stream>>>(out, W_lin, b_lin, out, x, nullptr, E);
    // res_after x2
    resfused_k<<<gb, NT, 0, stream>>>(out, out, resaW, resaB, E);
    resfused_k<<<gb, NT, 0, stream>>>(out, out, resaW + 2 * HCH * HCH, resaB + 2 * HCH, E);
}

// Round 3
// 4197.771 us; speedup vs baseline: 4.6991x; 1.7093x over previous
//
#include <hip/hip_runtime.h>
#include <cstdint>
#include <cstddef>

#define HCH 192
#define ICH 64
#define NRAD 6
#define SBFD 42

constexpr int NT = 256;

using bfrag = __attribute__((ext_vector_type(8))) short;  // 8 bf16 (4 VGPRs)
using f32x4 = __attribute__((ext_vector_type(4))) float;

#define MFMA16(a, b, c) __builtin_amdgcn_mfma_f32_16x16x32_bf16(a, b, c, 0, 0, 0)

__device__ __forceinline__ float silu_f(float v) {
    return v / (1.0f + __expf(-v));
}

__device__ __forceinline__ unsigned short f2bf(float x) {
    union { float f; unsigned u; } v; v.f = x;
    return (unsigned short)((v.u + 0x7FFFu + ((v.u >> 16) & 1u)) >> 16);
}

__device__ __forceinline__ bfrag pack8(float4 a, float4 b) {
    bfrag r;
    r[0] = (short)f2bf(a.x); r[1] = (short)f2bf(a.y);
    r[2] = (short)f2bf(a.z); r[3] = (short)f2bf(a.w);
    r[4] = (short)f2bf(b.x); r[5] = (short)f2bf(b.y);
    r[6] = (short)f2bf(b.z); r[7] = (short)f2bf(b.w);
    return r;
}

// ---------------- weight prep: fp32 [K][N] -> bf16 transposed [N][K] ----------------
// Wt layout: 9 x (192x192) [kj, ji, lin, rb0_0, rb0_1, ra0_0, ra0_1, ra1_0, ra1_1]
// then down [64][192], then up [192][64]
#define WSEG 36864
#define WT_DOWN (9 * WSEG)
#define WT_UP   (9 * WSEG + 12288)
#define WT_TOTAL (9 * WSEG + 2 * 12288)

__global__ __launch_bounds__(NT) void prep_k(
    const float* __restrict__ W_kj, const float* __restrict__ W_ji,
    const float* __restrict__ W_lin, const float* __restrict__ resbW,
    const float* __restrict__ resaW, const float* __restrict__ W_down,
    const float* __restrict__ W_up, unsigned short* __restrict__ Wt)
{
    int i = blockIdx.x * NT + threadIdx.x;
    if (i < 9 * WSEG) {
        int seg = i / WSEG, r = i % WSEG;
        int k = r / HCH, n = r % HCH;
        const float* src =
            seg == 0 ? W_kj : seg == 1 ? W_ji : seg == 2 ? W_lin :
            seg <= 4 ? resbW + (seg - 3) * WSEG : resaW + (seg - 5) * WSEG;
        Wt[seg * WSEG + n * HCH + k] = f2bf(src[r]);
    } else if (i < WT_DOWN + 12288) {
        int r = i - WT_DOWN;
        int k = r / ICH, n = r % ICH;           // W_down [192][64]
        Wt[WT_DOWN + n * HCH + k] = f2bf(W_down[r]);
    } else if (i < WT_TOTAL) {
        int r = i - WT_UP;
        int k = r / HCH, n = r % HCH;           // W_up [64][192]
        Wt[WT_UP + n * ICH + k] = f2bf(W_up[r]);
    }
}

// wc_rbf[6,192] = W_rbf1[6,8] @ W_rbf2[8,192]  (kept fp32)
__global__ void wc_k(const float* __restrict__ W_rbf1, const float* __restrict__ W_rbf2,
                     float* __restrict__ wc)
{
    int tid = blockIdx.x * blockDim.x + threadIdx.x;
    if (tid < NRAD * HCH) {
        int r = tid / HCH, c = tid % HCH;
        float a = 0.f;
        #pragma unroll
        for (int b = 0; b < 8; ++b) a += W_rbf1[r * 8 + b] * W_rbf2[b * HCH + c];
        wc[tid] = a;
    }
}

// ---------------- MFMA kernel 1: x -> x64 (W_kj + rbf modulate + W_down) ----------------
__global__ __launch_bounds__(NT) void fused12_k(
    const float* __restrict__ x, const unsigned short* __restrict__ Wt_kj,
    const float* __restrict__ b_kj, const float* __restrict__ rbf,
    const float* __restrict__ wc, const unsigned short* __restrict__ Wt_down,
    float* __restrict__ x64, int E)
{
    __shared__ unsigned short u_s[64][200];
    __shared__ float wc_s[NRAD * HCH];
    const int tid = threadIdx.x;
    const int lane = tid & 63, w = tid >> 6;
    const int row0 = blockIdx.x * 64;
    const int lr = lane & 15, lq = lane >> 4;
    const int kq = lq * 8;

    for (int i = tid; i < NRAD * HCH; i += NT) wc_s[i] = wc[i];

    const int ra = row0 + w * 16 + lr;
    const bool rav = ra < E;

    f32x4 acc[12];
    #pragma unroll
    for (int t = 0; t < 12; ++t) acc[t] = (f32x4){0.f, 0.f, 0.f, 0.f};

    #pragma unroll
    for (int ks = 0; ks < 6; ++ks) {
        const int k0 = ks * 32;
        float4 a0 = make_float4(0,0,0,0), a1 = make_float4(0,0,0,0);
        if (rav) {
            a0 = *(const float4*)(x + (size_t)ra * HCH + k0 + kq);
            a1 = *(const float4*)(x + (size_t)ra * HCH + k0 + kq + 4);
        }
        bfrag a = pack8(a0, a1);
        #pragma unroll
        for (int t = 0; t < 12; ++t) {
            bfrag b = *(const bfrag*)(Wt_kj + (size_t)(t * 16 + lr) * HCH + k0 + kq);
            acc[t] = MFMA16(a, b, acc[t]);
        }
    }
    __syncthreads();   // wc_s ready
    #pragma unroll
    for (int r = 0; r < 4; ++r) {
        int rloc = lq * 4 + r;
        int grow = row0 + w * 16 + rloc;
        float rb[NRAD];
        #pragma unroll
        for (int q = 0; q < NRAD; ++q) rb[q] = 0.f;
        if (grow < E) {
            #pragma unroll
            for (int q = 0; q < NRAD; ++q) rb[q] = rbf[(size_t)grow * NRAD + q];
        }
        #pragma unroll
        for (int t = 0; t < 12; ++t) {
            int col = t * 16 + lr;
            float sv = silu_f(acc[t][r] + b_kj[col]);
            float rh = 0.f;
            #pragma unroll
            for (int q = 0; q < NRAD; ++q) rh += rb[q] * wc_s[q * HCH + col];
            u_s[w * 16 + rloc][col] = f2bf(sv * rh);
        }
    }
    __syncthreads();   // u_s visible (cross-lane)

    f32x4 acc2[4];
    #pragma unroll
    for (int t = 0; t < 4; ++t) acc2[t] = (f32x4){0.f, 0.f, 0.f, 0.f};
    #pragma unroll
    for (int ks = 0; ks < 6; ++ks) {
        const int k0 = ks * 32;
        bfrag a = *(const bfrag*)&u_s[w * 16 + lr][k0 + kq];
        #pragma unroll
        for (int t = 0; t < 4; ++t) {
            bfrag b = *(const bfrag*)(Wt_down + (size_t)(t * 16 + lr) * HCH + k0 + kq);
            acc2[t] = MFMA16(a, b, acc2[t]);
        }
    }
    #pragma unroll
    for (int r = 0; r < 4; ++r) {
        int grow = row0 + w * 16 + lq * 4 + r;
        if (grow >= E) continue;
        #pragma unroll
        for (int t = 0; t < 4; ++t)
            x64[(size_t)grow * ICH + t * 16 + lr] = silu_f(acc2[t][r]);
    }
}

// ---------------- MFMA kernel 2: out = silu(x@W_ji + b_ji) + silu(agg@W_up) ----------------
__global__ __launch_bounds__(NT) void combine_k(
    const float* __restrict__ x, const unsigned short* __restrict__ Wt_ji,
    const float* __restrict__ b_ji, const float* __restrict__ agg,
    const unsigned short* __restrict__ Wt_up, float* __restrict__ out, int E)
{
    const int tid = threadIdx.x;
    const int lane = tid & 63, w = tid >> 6;
    const int row0 = blockIdx.x * 64;
    const int lr = lane & 15, lq = lane >> 4;
    const int kq = lq * 8;
    const int ra = row0 + w * 16 + lr;
    const bool rav = ra < E;

    f32x4 acc[12], acc2[12];
    #pragma unroll
    for (int t = 0; t < 12; ++t) {
        acc[t] = (f32x4){0.f, 0.f, 0.f, 0.f};
        acc2[t] = (f32x4){0.f, 0.f, 0.f, 0.f};
    }

    #pragma unroll
    for (int ks = 0; ks < 6; ++ks) {
        const int k0 = ks * 32;
        float4 a0 = make_float4(0,0,0,0), a1 = make_float4(0,0,0,0);
        if (rav) {
            a0 = *(const float4*)(x + (size_t)ra * HCH + k0 + kq);
            a1 = *(const float4*)(x + (size_t)ra * HCH + k0 + kq + 4);
        }
        bfrag a = pack8(a0, a1);
        #pragma unroll
        for (int t = 0; t < 12; ++t) {
            bfrag b = *(const bfrag*)(Wt_ji + (size_t)(t * 16 + lr) * HCH + k0 + kq);
            acc[t] = MFMA16(a, b, acc[t]);
        }
    }
    #pragma unroll
    for (int ks = 0; ks < 2; ++ks) {
        const int k0 = ks * 32;
        float4 a0 = make_float4(0,0,0,0), a1 = make_float4(0,0,0,0);
        if (rav) {
            a0 = *(const float4*)(agg + (size_t)ra * ICH + k0 + kq);
            a1 = *(const float4*)(agg + (size_t)ra * ICH + k0 + kq + 4);
        }
        bfrag a = pack8(a0, a1);
        #pragma unroll
        for (int t = 0; t < 12; ++t) {
            bfrag b = *(const bfrag*)(Wt_up + (size_t)(t * 16 + lr) * ICH + k0 + kq);
            acc2[t] = MFMA16(a, b, acc2[t]);
        }
    }
    #pragma unroll
    for (int r = 0; r < 4; ++r) {
        int grow = row0 + w * 16 + lq * 4 + r;
        if (grow >= E) continue;
        #pragma unroll
        for (int t = 0; t < 12; ++t) {
            int col = t * 16 + lr;
            out[(size_t)grow * HCH + col] =
                silu_f(acc[t][r] + b_ji[col]) + silu_f(acc2[t][r]);
        }
    }
}

// ---------------- MFMA kernel 3: residual layer, in-place ----------------
__global__ __launch_bounds__(NT) void res_k(
    float* __restrict__ h, const unsigned short* __restrict__ Wt0,
    const unsigned short* __restrict__ Wt1, const float* __restrict__ b0,
    const float* __restrict__ b1, int E)
{
    __shared__ float h_s[64][196];
    __shared__ unsigned short t_s[64][200];
    const int tid = threadIdx.x;
    const int lane = tid & 63, w = tid >> 6;
    const int row0 = blockIdx.x * 64;
    const int lr = lane & 15, lq = lane >> 4;
    const int kq = lq * 8;

    for (int i = tid; i < 64 * 48; i += NT) {
        int r = i / 48, c4 = (i % 48) * 4;
        int gr = row0 + r;
        float4 v = make_float4(0,0,0,0);
        if (gr < E) v = *(const float4*)(h + (size_t)gr * HCH + c4);
        *(float4*)&h_s[r][c4] = v;
    }
    __syncthreads();

    f32x4 acc[12];
    #pragma unroll
    for (int t = 0; t < 12; ++t) acc[t] = (f32x4){0.f, 0.f, 0.f, 0.f};

    #pragma unroll
    for (int ks = 0; ks < 6; ++ks) {
        const int k0 = ks * 32;
        float4 a0 = *(const float4*)&h_s[w * 16 + lr][k0 + kq];
        float4 a1 = *(const float4*)&h_s[w * 16 + lr][k0 + kq + 4];
        bfrag a = pack8(a0, a1);
        #pragma unroll
        for (int t = 0; t < 12; ++t) {
            bfrag b = *(const bfrag*)(Wt0 + (size_t)(t * 16 + lr) * HCH + k0 + kq);
            acc[t] = MFMA16(a, b, acc[t]);
        }
    }
    #pragma unroll
    for (int r = 0; r < 4; ++r) {
        int rloc = lq * 4 + r;
        #pragma unroll
        for (int t = 0; t < 12; ++t) {
            int col = t * 16 + lr;
            t_s[w * 16 + rloc][col] = f2bf(silu_f(acc[t][r] + b0[col]));
        }
    }
    __syncthreads();   // t_s visible (cross-lane)

    #pragma unroll
    for (int t = 0; t < 12; ++t) acc[t] = (f32x4){0.f, 0.f, 0.f, 0.f};
    #pragma unroll
    for (int ks = 0; ks < 6; ++ks) {
        const int k0 = ks * 32;
        bfrag a = *(const bfrag*)&t_s[w * 16 + lr][k0 + kq];
        #pragma unroll
        for (int t = 0; t < 12; ++t) {
            bfrag b = *(const bfrag*)(Wt1 + (size_t)(t * 16 + lr) * HCH + k0 + kq);
            acc[t] = MFMA16(a, b, acc[t]);
        }
    }
    #pragma unroll
    for (int r = 0; r < 4; ++r) {
        int rloc = lq * 4 + r;
        int grow = row0 + w * 16 + rloc;
        if (grow >= E) continue;
        #pragma unroll
        for (int t = 0; t < 12; ++t) {
            int col = t * 16 + lr;
            h[(size_t)grow * HCH + col] =
                h_s[rloc + w * 16][col] + silu_f(acc[t][r] + b1[col]);
        }
    }
}

// ---------------- MFMA kernel 4: h = silu(h@W_lin + b_lin) + x, in-place ----------------
__global__ __launch_bounds__(NT) void lin_k(
    float* __restrict__ h, const unsigned short* __restrict__ Wt_lin,
    const float* __restrict__ b_lin, const float* __restrict__ x, int E)
{
    const int tid = threadIdx.x;
    const int lane = tid & 63, w = tid >> 6;
    const int row0 = blockIdx.x * 64;
    const int lr = lane & 15, lq = lane >> 4;
    const int kq = lq * 8;
    const int ra = row0 + w * 16 + lr;
    const bool rav = ra < E;

    f32x4 acc[12];
    #pragma unroll
    for (int t = 0; t < 12; ++t) acc[t] = (f32x4){0.f, 0.f, 0.f, 0.f};

    #pragma unroll
    for (int ks = 0; ks < 6; ++ks) {
        const int k0 = ks * 32;
        float4 a0 = make_float4(0,0,0,0), a1 = make_float4(0,0,0,0);
        if (rav) {
            a0 = *(const float4*)(h + (size_t)ra * HCH + k0 + kq);
            a1 = *(const float4*)(h + (size_t)ra * HCH + k0 + kq + 4);
        }
        bfrag a = pack8(a0, a1);
        #pragma unroll
        for (int t = 0; t < 12; ++t) {
            bfrag b = *(const bfrag*)(Wt_lin + (size_t)(t * 16 + lr) * HCH + k0 + kq);
            acc[t] = MFMA16(a, b, acc[t]);
        }
    }
    #pragma unroll
    for (int r = 0; r < 4; ++r) {
        int grow = row0 + w * 16 + lq * 4 + r;
        if (grow >= E) continue;
        #pragma unroll
        for (int t = 0; t < 12; ++t) {
            int col = t * 16 + lr;
            h[(size_t)grow * HCH + col] =
                silu_f(acc[t][r] + b_lin[col]) + x[(size_t)grow * HCH + col];
        }
    }
}

// ---------------- CSR scatter->gather pipeline (unchanged from round 2) ----------------
__global__ __launch_bounds__(256) void pcount_k(
    const float* __restrict__ sbf, const int* __restrict__ idx_ji,
    const float* __restrict__ w1, float* __restrict__ p, int* __restrict__ counts, int T)
{
    int t = blockIdx.x * 256 + threadIdx.x;
    if (t >= T) return;
    const float* sp = sbf + (size_t)t * SBFD;
    float acc[8];
    #pragma unroll
    for (int b = 0; b < 8; ++b) acc[b] = 0.f;
    #pragma unroll
    for (int r = 0; r < SBFD; r += 2) {
        float2 v = *(const float2*)(sp + r);
        #pragma unroll
        for (int b = 0; b < 8; ++b)
            acc[b] += v.x * w1[r * 8 + b] + v.y * w1[(r + 1) * 8 + b];
    }
    float4* pp = (float4*)(p + (size_t)t * 8);
    pp[0] = make_float4(acc[0], acc[1], acc[2], acc[3]);
    pp[1] = make_float4(acc[4], acc[5], acc[6], acc[7]);
    atomicAdd(&counts[idx_ji[t]], 1);
}

__global__ __launch_bounds__(256) void psum1_k(const int* __restrict__ counts,
                                               int* __restrict__ bsum, int E) {
    __shared__ int s[256];
    int base = blockIdx.x * 1024;
    int tid = threadIdx.x;
    int sum = 0;
    #pragma unroll
    for (int j = 0; j < 4; ++j) { int i = base + j * 256 + tid; if (i < E) sum += counts[i]; }
    s[tid] = sum; __syncthreads();
    for (int off = 128; off > 0; off >>= 1) {
        if (tid < off) s[tid] += s[tid + off];
        __syncthreads();
    }
    if (tid == 0) bsum[blockIdx.x] = s[0];
}

__global__ __launch_bounds__(512) void psum2_k(int* bsum, int G) {
    __shared__ int s[512];
    int tid = threadIdx.x;
    s[tid] = (tid < G) ? bsum[tid] : 0;
    for (int off = 1; off < 512; off <<= 1) {
        __syncthreads();
        int v = (tid >= off) ? s[tid - off] : 0;
        __syncthreads();
        s[tid] += v;
    }
    __syncthreads();
    if (tid < G) bsum[tid] = (tid == 0) ? 0 : s[tid - 1];
}

__global__ __launch_bounds__(256) void psum3_k(const int* __restrict__ counts,
                                               const int* __restrict__ bsum,
                                               int* __restrict__ start, int E) {
    __shared__ int s[256];
    int tid = threadIdx.x;
    int base = blockIdx.x * 1024 + tid * 4;
    int v[4]; int loc = 0;
    #pragma unroll
    for (int j = 0; j < 4; ++j) { v[j] = (base + j < E) ? counts[base + j] : 0; loc += v[j]; }
    s[tid] = loc;
    for (int off = 1; off < 256; off <<= 1) {
        __syncthreads();
        int t2 = (tid >= off) ? s[tid - off] : 0;
        __syncthreads();
        s[tid] += t2;
    }
    __syncthreads();
    int run = bsum[blockIdx.x] + s[tid] - loc;
    #pragma unroll
    for (int j = 0; j < 4; ++j) { if (base + j < E) start[base + j] = run; run += v[j]; }
}

__global__ __launch_bounds__(256) void fill_k(const int* __restrict__ idx_ji,
                                              int* __restrict__ start,
                                              int* __restrict__ trip, int T) {
    int t = blockIdx.x * 256 + threadIdx.x;
    if (t >= T) return;
    int pos = atomicAdd(&start[idx_ji[t]], 1);
    trip[pos] = t;
}

__global__ __launch_bounds__(256) void gather_k(
    const int* __restrict__ trip, const int* __restrict__ idx_kj,
    const float* __restrict__ p, const float* __restrict__ x64,
    const int* __restrict__ start, const int* __restrict__ counts,
    const float* __restrict__ w2, float* __restrict__ agg, int E)
{
    __shared__ float w2s[8 * 64];
    int tid = threadIdx.x;
    for (int i = tid; i < 8 * 64; i += 256) w2s[i] = w2[i];
    __syncthreads();

    int wave = (blockIdx.x * 256 + tid) >> 6;
    int lane = tid & 63;
    if (wave >= E) return;

    int n = counts[wave];
    int end = start[wave];
    int begin = end - n;

    float acc = 0.f;
    for (int i = begin; i < end; ++i) {
        int t = trip[i];
        int kj = idx_kj[t];
        float p8 = p[(size_t)t * 8 + (lane & 7)];
        float xv = x64[(size_t)kj * ICH + lane];
        float sc = 0.f;
        #pragma unroll
        for (int b = 0; b < 8; ++b)
            sc += __shfl(p8, b, 64) * w2s[b * 64 + lane];
        acc += sc * xv;
    }
    agg[(size_t)wave * ICH + lane] = acc;
}

extern "C" void kernel_launch(void* const* d_in, const int* in_sizes, int n_in,
                              void* d_out, int out_size, void* d_ws, size_t ws_size,
                              hipStream_t stream) {
    const float* x      = (const float*)d_in[0];
    const float* rbf    = (const float*)d_in[1];
    const float* sbf    = (const float*)d_in[2];
    const int*   idx_kj = (const int*)d_in[3];
    const int*   idx_ji = (const int*)d_in[4];
    const float* W_rbf1 = (const float*)d_in[5];
    const float* W_rbf2 = (const float*)d_in[6];
    const float* W_sbf1 = (const float*)d_in[7];
    const float* W_sbf2 = (const float*)d_in[8];
    const float* W_kj   = (const float*)d_in[9];
    const float* b_kj   = (const float*)d_in[10];
    const float* W_ji   = (const float*)d_in[11];
    const float* b_ji   = (const float*)d_in[12];
    const float* W_down = (const float*)d_in[13];
    const float* W_up   = (const float*)d_in[14];
    const float* resbW  = (const float*)d_in[15];
    const float* resbB  = (const float*)d_in[16];
    const float* W_lin  = (const float*)d_in[17];
    const float* b_lin  = (const float*)d_in[18];
    const float* resaW  = (const float*)d_in[19];
    const float* resaB  = (const float*)d_in[20];

    const int E = in_sizes[0] / HCH;
    const int T = in_sizes[3];
    float* out = (float*)d_out;

    // ws: p[T,8] | x64[E,64] | agg[E,64] | wc_rbf | counts[E] | start[E] | bsum[512] | trip[T] | Wt(bf16)
    float* p      = (float*)d_ws;
    float* x64    = p + (size_t)T * 8;
    float* agg    = x64 + (size_t)E * ICH;
    float* wc_rbf = agg + (size_t)E * ICH;
    int*   counts = (int*)(wc_rbf + NRAD * HCH);
    int*   start  = counts + E;
    int*   bsum   = start + E;
    int*   trip   = bsum + 512;
    unsigned short* Wt = (unsigned short*)(trip + T);

    const unsigned short* Wt_kj   = Wt;
    const unsigned short* Wt_ji   = Wt + 1 * WSEG;
    const unsigned short* Wt_lin  = Wt + 2 * WSEG;
    const unsigned short* Wt_rb0  = Wt + 3 * WSEG;   // W0, W1 at +WSEG
    const unsigned short* Wt_ra0  = Wt + 5 * WSEG;
    const unsigned short* Wt_ra1  = Wt + 7 * WSEG;
    const unsigned short* Wt_down = Wt + WT_DOWN;
    const unsigned short* Wt_up   = Wt + WT_UP;

    const int gb64 = (E + 63) / 64;
    const int gt = (T + 255) / 256;
    const int gscan = (E + 1023) / 1024;

    wc_k<<<(NRAD * HCH + NT - 1) / NT, NT, 0, stream>>>(W_rbf1, W_rbf2, wc_rbf);
    prep_k<<<(WT_TOTAL + NT - 1) / NT, NT, 0, stream>>>(W_kj, W_ji, W_lin, resbW, resaW,
                                                        W_down, W_up, Wt);

    // CSR build
    hipMemsetAsync(counts, 0, (size_t)E * sizeof(int), stream);
    pcount_k<<<gt, 256, 0, stream>>>(sbf, idx_ji, W_sbf1, p, counts, T);
    psum1_k<<<gscan, 256, 0, stream>>>(counts, bsum, E);
    psum2_k<<<1, 512, 0, stream>>>(bsum, gscan);
    psum3_k<<<gscan, 256, 0, stream>>>(counts, bsum, start, E);
    fill_k<<<gt, 256, 0, stream>>>(idx_ji, start, trip, T);

    // x -> x64
    fused12_k<<<gb64, NT, 0, stream>>>(x, Wt_kj, b_kj, rbf, wc_rbf, Wt_down, x64, E);
    // agg
    gather_k<<<(E + 3) / 4, 256, 0, stream>>>(trip, idx_kj, p, x64, start, counts, W_sbf2, agg, E);
    // h = silu(x@W_ji+b) + silu(agg@W_up)
    combine_k<<<gb64, NT, 0, stream>>>(x, Wt_ji, b_ji, agg, Wt_up, out, E);
    // res_before
    res_k<<<gb64, NT, 0, stream>>>(out, Wt_rb0, Wt_rb0 + WSEG, resbB, resbB + HCH, E);
    // h = silu(h@W_lin + b_lin) + x
    lin_k<<<gb64, NT, 0, stream>>>(out, Wt_lin, b_lin, x, E);
    // res_after x2
    res_k<<<gb64, NT, 0, stream>>>(out, Wt_ra0, Wt_ra0 + WSEG, resaB, resaB + HCH, E);
    res_k<<<gb64, NT, 0, stream>>>(out, Wt_ra1, Wt_ra1 + WSEG, resaB + 2 * HCH, resaB + 3 * HCH, E);
}